// Round 2
// baseline (398.642 us; speedup 1.0000x reference)
//
#include <hip/hip_runtime.h>
#include <stdint.h>

#define EPS_C 0.01f
#define THRESH 0.8f

constexpr int Nn = 8192;
constexpr int Ff = 256;
constexpr int Ee = 262144;

__device__ __forceinline__ float b2f(unsigned short u) {
  union { uint32_t i; float f; } v; v.i = ((uint32_t)u) << 16; return v.f;
}
__device__ __forceinline__ unsigned short f2b(float f) {
  union { uint32_t i; float f; } v; v.f = f;
  uint32_t r = v.i + 0x7FFFu + ((v.i >> 16) & 1u);
  return (unsigned short)(r >> 16);
}

// ---------- K1: column sums of z (f32) ----------
__global__ void k_colsum(const float* __restrict__ z, float* __restrict__ colsum) {
  int t = threadIdx.x;              // column 0..255
  int r0 = blockIdx.x * 128;        // 64 blocks * 128 rows
  float acc = 0.f;
#pragma unroll 8
  for (int r = 0; r < 128; ++r)
    acc += z[(size_t)(r0 + r) * Ff + t];
  atomicAdd(&colsum[t], acc);
}

// ---------- K2: per-node weight w ----------
__global__ void k_w(const int* __restrict__ k2u, const int* __restrict__ u2k,
                    float* __restrict__ w) {
  int n = blockIdx.x * 256 + threadIdx.x;
  w[n] = powf(0.9f, (float)k2u[n]) + 1.f - powf(0.9f, (float)u2k[n]);
}

// ---------- K3: cov = zm^T zm (split over 8 row-chunks, atomic) ----------
__global__ void k_cov(const float* __restrict__ z,
                      const float* __restrict__ colsum, float* __restrict__ cov) {
  int tx = threadIdx.x & 15, ty = threadIdx.x >> 4;
  int a = blockIdx.y * 16 + ty;
  int b = blockIdx.x * 16 + tx;
  int r0 = blockIdx.z * 1024;
  float ma = colsum[a] * (1.f / 8192.f), mb = colsum[b] * (1.f / 8192.f);
  float acc = 0.f;
  const float* zp = z + (size_t)r0 * Ff;
#pragma unroll 4
  for (int r = 0; r < 1024; ++r) {
    float va = zp[(size_t)r * Ff + a] - ma;
    float vb = zp[(size_t)r * Ff + b] - mb;
    acc = fmaf(va, vb, acc);
  }
  atomicAdd(&cov[a * Ff + b], acc);
}

// ---------- K4: cor from cov ----------
__global__ void k_cor(const float* __restrict__ cov, float* __restrict__ cor) {
  int idx = blockIdx.x * 256 + threadIdx.x;
  int a = idx >> 8, b = idx & 255;
  float c = 0.f;
  if (a != b) {
    float denom = sqrtf(cov[a * Ff + a] * cov[b * Ff + b]);
    c = cov[a * Ff + b] / denom;
    if (c != c) c = 0.f;                 // nan_to_num
    c = fminf(1.f, fmaxf(-1.f, c));      // clip
  }
  cor[idx] = c;
}

// ---------- K5: z2 = z + EPS*(w*zm)@cor, stored bf16 ----------
__global__ __launch_bounds__(256) void k_z2(const float* __restrict__ z,
    const float* __restrict__ colsum, const float* __restrict__ w,
    const float* __restrict__ cor, unsigned short* __restrict__ z2b) {
  __shared__ float Wl[32 * 256];
  int t = threadIdx.x;
  int row0 = blockIdx.x * 32;
  float mt = colsum[t] * (1.f / 8192.f);
  for (int rr = 0; rr < 32; ++rr) {
    int row = row0 + rr;
    Wl[rr * 256 + t] = w[row] * (z[(size_t)row * Ff + t] - mt);
  }
  __syncthreads();
  int tc = t & 63, tr = t >> 6;   // thread owns cols [tc*4, tc*4+4), rows [tr*8, tr*8+8)
  float acc[8][4];
#pragma unroll
  for (int i = 0; i < 8; ++i)
#pragma unroll
    for (int j = 0; j < 4; ++j) acc[i][j] = 0.f;
  const float* corc = cor + tc * 4;
  for (int k = 0; k < 256; ++k) {
    float4 c4 = *(const float4*)(corc + (size_t)k * 256);
#pragma unroll
    for (int rr = 0; rr < 8; ++rr) {
      float wv = Wl[(tr * 8 + rr) * 256 + k];
      acc[rr][0] = fmaf(wv, c4.x, acc[rr][0]);
      acc[rr][1] = fmaf(wv, c4.y, acc[rr][1]);
      acc[rr][2] = fmaf(wv, c4.z, acc[rr][2]);
      acc[rr][3] = fmaf(wv, c4.w, acc[rr][3]);
    }
  }
#pragma unroll
  for (int rr = 0; rr < 8; ++rr) {
    int row = row0 + tr * 8 + rr;
    float4 zv = *(const float4*)(z + (size_t)row * Ff + tc * 4);
    ushort4 o;
    o.x = f2b(zv.x + EPS_C * acc[rr][0]);
    o.y = f2b(zv.y + EPS_C * acc[rr][1]);
    o.z = f2b(zv.z + EPS_C * acc[rr][2]);
    o.w = f2b(zv.w + EPS_C * acc[rr][3]);
    *(ushort4*)(z2b + (size_t)row * Ff + tc * 4) = o;
  }
}

// ---------- K6: row norms of z2 ----------
__global__ void k_norms(const unsigned short* __restrict__ z2b, float* __restrict__ norms) {
  int lane = threadIdx.x & 63;
  int row = blockIdx.x * 4 + (threadIdx.x >> 6);
  ushort4 u = *((const ushort4*)(z2b + (size_t)row * Ff) + lane);
  float x0 = b2f(u.x), x1 = b2f(u.y), x2 = b2f(u.z), x3 = b2f(u.w);
  float s = x0 * x0 + x1 * x1 + x2 * x2 + x3 * x3;
#pragma unroll
  for (int m = 1; m < 64; m <<= 1) s += __shfl_xor(s, m);
  if (lane == 0) norms[row] = fmaxf(sqrtf(s), 1e-8f);
}

// ---------- K7: adjacency bitmask ----------
__global__ void k_adj(const int* __restrict__ ei, const int* __restrict__ ej,
                      unsigned int* __restrict__ adj) {
  int e = blockIdx.x * 256 + threadIdx.x;
  unsigned int i = (unsigned int)ei[e], j = (unsigned int)ej[e];
  size_t b1 = (size_t)i * Nn + j;
  size_t b2 = (size_t)j * Nn + i;
  atomicOr(&adj[b1 >> 5], 1u << (b1 & 31));
  atomicOr(&adj[b2 >> 5], 1u << (b2 & 31));
}

// ---------- K8: per-edge cosine, scatter by source ----------
__global__ void k_edge(const int* __restrict__ ei, const int* __restrict__ ej,
                       const unsigned short* __restrict__ z2b,
                       const float* __restrict__ norms,
                       float* __restrict__ scores, float* __restrict__ deg) {
  int lane = threadIdx.x & 63;
  int e = blockIdx.x * 4 + (threadIdx.x >> 6);
  int i = ei[e], j = ej[e];
  ushort4 ui = *((const ushort4*)(z2b + (size_t)i * Ff) + lane);
  ushort4 uj = *((const ushort4*)(z2b + (size_t)j * Ff) + lane);
  float d = b2f(ui.x) * b2f(uj.x) + b2f(ui.y) * b2f(uj.y) +
            b2f(ui.z) * b2f(uj.z) + b2f(ui.w) * b2f(uj.w);
#pragma unroll
  for (int m = 1; m < 64; m <<= 1) d += __shfl_xor(d, m);
  if (lane == 0) {
    float sim = d / (norms[i] * norms[j]);
    atomicAdd(&scores[i], sim);
    atomicAdd(&deg[i], 1.f);
  }
}

// ---------- K9: homophily reduce ----------
__global__ void k_homo(const float* __restrict__ scores, const float* __restrict__ deg,
                       double* __restrict__ hsum) {
  __shared__ float red[4];
  int n = blockIdx.x * 256 + threadIdx.x;
  float dg = deg[n];
  float v = scores[n] / (dg == 0.f ? 1.f : dg);
#pragma unroll
  for (int m = 1; m < 64; m <<= 1) v += __shfl_xor(v, m);
  int lane = threadIdx.x & 63, wv = threadIdx.x >> 6;
  if (lane == 0) red[wv] = v;
  __syncthreads();
  if (threadIdx.x == 0) atomicAdd(hsum, (double)(red[0] + red[1] + red[2] + red[3]));
}

// ---------- K10: fused penalty GEMM (z2 @ z2^T, masked thresholded sum) ----------
typedef __bf16 bf16x8 __attribute__((ext_vector_type(8)));
typedef float f32x4 __attribute__((ext_vector_type(4)));

__global__ __launch_bounds__(256, 2) void k_penalty(const unsigned short* __restrict__ z2b,
    const unsigned int* __restrict__ adj, double* __restrict__ psum) {
  int bc = blockIdx.x, br = blockIdx.y;
  if (br > bc) return;                       // symmetry: upper-triangular tiles only
  __shared__ __align__(16) unsigned short As[128 * 64];
  __shared__ __align__(16) unsigned short Bs[128 * 64];
  __shared__ float red[4];
  int t = threadIdx.x;
  int lane = t & 63;
  int wv = t >> 6;
  int wr = wv >> 1, wc = wv & 1;             // 2x2 waves, each 64x64
  int quad = lane >> 4;
  int l15 = lane & 15;
  int arow0 = br * 128, brow0 = bc * 128;

  f32x4 acc[4][4];
#pragma unroll
  for (int i = 0; i < 4; ++i)
#pragma unroll
    for (int j = 0; j < 4; ++j) acc[i][j] = (f32x4){0.f, 0.f, 0.f, 0.f};

  for (int kk = 0; kk < 4; ++kk) {
    int k0 = kk * 64;
    // stage 128x64 A and B tiles; XOR-swizzle k-granules within each row
#pragma unroll
    for (int it = 0; it < 4; ++it) {
      int s = it * 256 + t;                  // LDS granule index (16B granules)
      int r = s >> 3;
      int g = (s & 7) ^ (r & 7);             // global k-granule stored at this slot
      const unsigned short* ga = z2b + (size_t)(arow0 + r) * Ff + k0 + g * 8;
      const unsigned short* gb = z2b + (size_t)(brow0 + r) * Ff + k0 + g * 8;
      __builtin_amdgcn_global_load_lds((const __attribute__((address_space(1))) void*)ga,
                                       (__attribute__((address_space(3))) void*)(As + s * 8),
                                       16, 0, 0);
      __builtin_amdgcn_global_load_lds((const __attribute__((address_space(1))) void*)gb,
                                       (__attribute__((address_space(3))) void*)(Bs + s * 8),
                                       16, 0, 0);
    }
    __syncthreads();
#pragma unroll
    for (int kc = 0; kc < 2; ++kc) {
      bf16x8 afr[4], bfr[4];
#pragma unroll
      for (int mt = 0; mt < 4; ++mt) {
        int rA = wr * 64 + mt * 16 + l15;
        int g = kc * 4 + quad;
        int gl = g ^ (rA & 7);
        afr[mt] = *(const bf16x8*)(As + ((size_t)rA * 8 + gl) * 8);
      }
#pragma unroll
      for (int nt = 0; nt < 4; ++nt) {
        int rB = wc * 64 + nt * 16 + l15;
        int g = kc * 4 + quad;
        int gl = g ^ (rB & 7);
        bfr[nt] = *(const bf16x8*)(Bs + ((size_t)rB * 8 + gl) * 8);
      }
#pragma unroll
      for (int mt = 0; mt < 4; ++mt)
#pragma unroll
        for (int nt = 0; nt < 4; ++nt)
          acc[mt][nt] = __builtin_amdgcn_mfma_f32_16x16x32_bf16(afr[mt], bfr[nt],
                                                                acc[mt][nt], 0, 0, 0);
    }
    __syncthreads();
  }

  // epilogue: masked thresholded sum with symmetry weights
  float local = 0.f;
  int a_base = arow0 + wr * 64;
  int b_base = brow0 + wc * 64;              // 64-aligned
#pragma unroll
  for (int mt = 0; mt < 4; ++mt) {
#pragma unroll
    for (int r = 0; r < 4; ++r) {
      int a = a_base + mt * 16 + quad * 4 + r;
      uint64_t bits = *(const uint64_t*)(adj + (size_t)a * 256 + (b_base >> 5));
#pragma unroll
      for (int nt = 0; nt < 4; ++nt) {
        float v = acc[mt][nt][r];
        int boff = nt * 16 + l15;
        bool conn = (bits >> boff) & 1ull;
        float wgt;
        if (br != bc) wgt = 2.f;
        else {
          int b = b_base + boff;
          wgt = (a < b) ? 2.f : (a == b ? 1.f : 0.f);
        }
        if (!conn && v > THRESH) local += wgt * v;
      }
    }
  }
#pragma unroll
  for (int m = 1; m < 64; m <<= 1) local += __shfl_xor(local, m);
  if (lane == 0) red[wv] = local;
  __syncthreads();
  if (t == 0) atomicAdd(psum, (double)(red[0] + red[1] + red[2] + red[3]));
}

// ---------- K11: combine ----------
__global__ void k_final(const double* __restrict__ hsum, const double* __restrict__ psum,
                        float* __restrict__ out) {
  if (threadIdx.x == 0) {
    double h = -(*hsum) / 8192.0;
    double p = (*psum) / (8192.0 * 8192.0);
    out[0] = (float)(h + p);
  }
}

extern "C" void kernel_launch(void* const* d_in, const int* in_sizes, int n_in,
                              void* d_out, int out_size, void* d_ws, size_t ws_size,
                              hipStream_t stream) {
  const float* z = (const float*)d_in[0];
  // d_in[1] = x_hat (unused by the reference)
  const int* ei = (const int*)d_in[2];
  const int* ej = ei + Ee;
  const int* k2u = (const int*)d_in[3];
  const int* u2k = (const int*)d_in[4];

  char* ws = (char*)d_ws;
  unsigned int* adj = (unsigned int*)(ws);             // 8 MiB
  float* cov        = (float*)(ws + 8388608);          // 256 KiB
  float* colsum     = (float*)(ws + 8650752);          // 1 KiB
  float* scores     = (float*)(ws + 8651776);          // 32 KiB
  float* deg        = (float*)(ws + 8684544);          // 32 KiB
  double* psum      = (double*)(ws + 8717312);
  double* hsum      = (double*)(ws + 8717320);
  const size_t ZERO_BYTES = 8717328;
  float* w          = (float*)(ws + 8718336);          // 32 KiB
  float* cor        = (float*)(ws + 8751104);          // 256 KiB
  unsigned short* z2b = (unsigned short*)(ws + 9013248); // 4 MiB
  float* norms      = (float*)(ws + 13207552);         // 32 KiB

  hipMemsetAsync(d_ws, 0, ZERO_BYTES, stream);
  k_colsum<<<64, 256, 0, stream>>>(z, colsum);
  k_w<<<32, 256, 0, stream>>>(k2u, u2k, w);
  k_adj<<<1024, 256, 0, stream>>>(ei, ej, adj);
  k_cov<<<dim3(16, 16, 8), 256, 0, stream>>>(z, colsum, cov);
  k_cor<<<256, 256, 0, stream>>>(cov, cor);
  k_z2<<<256, 256, 0, stream>>>(z, colsum, w, cor, z2b);
  k_norms<<<2048, 256, 0, stream>>>(z2b, norms);
  k_edge<<<65536, 256, 0, stream>>>(ei, ej, z2b, norms, scores, deg);
  k_homo<<<32, 256, 0, stream>>>(scores, deg, hsum);
  k_penalty<<<dim3(64, 64), 256, 0, stream>>>(z2b, adj, psum);
  k_final<<<1, 64, 0, stream>>>(hsum, psum, (float*)d_out);
}

// Round 3
// 258.898 us; speedup vs baseline: 1.5398x; 1.5398x over previous
//
#include <hip/hip_runtime.h>
#include <stdint.h>

#define EPS_C 0.01f
#define THRESH 0.8f

constexpr int Nn = 8192;
constexpr int Ff = 256;
constexpr int Ee = 262144;

__device__ __forceinline__ float b2f(unsigned short u) {
  union { uint32_t i; float f; } v; v.i = ((uint32_t)u) << 16; return v.f;
}
__device__ __forceinline__ unsigned short f2b(float f) {
  union { uint32_t i; float f; } v; v.f = f;
  uint32_t r = v.i + 0x7FFFu + ((v.i >> 16) & 1u);
  return (unsigned short)(r >> 16);
}

// ---------- K1: column sums of z (f32) ----------
__global__ void k_colsum(const float* __restrict__ z, float* __restrict__ colsum) {
  int t = threadIdx.x;              // column 0..255
  int r0 = blockIdx.x * 128;        // 64 blocks * 128 rows
  float acc = 0.f;
#pragma unroll 8
  for (int r = 0; r < 128; ++r)
    acc += z[(size_t)(r0 + r) * Ff + t];
  atomicAdd(&colsum[t], acc);
}

// ---------- K2: per-node weight w ----------
__global__ void k_w(const int* __restrict__ k2u, const int* __restrict__ u2k,
                    float* __restrict__ w) {
  int n = blockIdx.x * 256 + threadIdx.x;
  w[n] = powf(0.9f, (float)k2u[n]) + 1.f - powf(0.9f, (float)u2k[n]);
}

// ---------- K3a: transpose+quantize z -> zT bf16 [256][8192] ----------
__global__ void k_transpose(const float* __restrict__ z, unsigned short* __restrict__ zT) {
  __shared__ float Ls[64][65];
  int n0 = blockIdx.x * 64;
  int c0 = blockIdx.y * 64;
  int t = threadIdx.x;
  int r = t >> 4;        // 0..15
  int cq = t & 15;       // 0..15
#pragma unroll
  for (int i = 0; i < 4; ++i) {
    int row = r + 16 * i;
    float4 v = *(const float4*)(z + (size_t)(n0 + row) * Ff + c0 + cq * 4);
    Ls[row][cq * 4 + 0] = v.x;
    Ls[row][cq * 4 + 1] = v.y;
    Ls[row][cq * 4 + 2] = v.z;
    Ls[row][cq * 4 + 3] = v.w;
  }
  __syncthreads();
  int cr = t >> 4;       // row (feature) within tile
  int nq = t & 15;       // n-quad
#pragma unroll
  for (int i = 0; i < 4; ++i) {
    int c = cr + 16 * i;
    ushort4 o;
    o.x = f2b(Ls[nq * 4 + 0][c]);
    o.y = f2b(Ls[nq * 4 + 1][c]);
    o.z = f2b(Ls[nq * 4 + 2][c]);
    o.w = f2b(Ls[nq * 4 + 3][c]);
    *(ushort4*)(zT + (size_t)(c0 + c) * Nn + n0 + nq * 4) = o;
  }
}

// ---------- K3b: G = zT @ zT^T via MFMA, split-K=16 partials ----------
typedef __bf16 bf16x8 __attribute__((ext_vector_type(8)));
typedef float f32x4 __attribute__((ext_vector_type(4)));

__global__ __launch_bounds__(256, 2) void k_covg(const unsigned short* __restrict__ zT,
                                                 float* __restrict__ covp) {
  int bx = blockIdx.x, by = blockIdx.y, p = blockIdx.z;
  __shared__ __align__(16) unsigned short As[128 * 64];
  __shared__ __align__(16) unsigned short Bs[128 * 64];
  int t = threadIdx.x;
  int lane = t & 63, wv = t >> 6;
  int wr = wv >> 1, wc = wv & 1;
  int quad = lane >> 4, l15 = lane & 15;
  int a0 = by * 128, b0 = bx * 128;

  f32x4 acc[4][4];
#pragma unroll
  for (int i = 0; i < 4; ++i)
#pragma unroll
    for (int j = 0; j < 4; ++j) acc[i][j] = (f32x4){0.f, 0.f, 0.f, 0.f};

  for (int kk = 0; kk < 8; ++kk) {
    int k0 = p * 512 + kk * 64;
#pragma unroll
    for (int it = 0; it < 4; ++it) {
      int s = it * 256 + t;
      int r = s >> 3;
      int g = (s & 7) ^ (r & 7);
      const unsigned short* ga = zT + (size_t)(a0 + r) * Nn + k0 + g * 8;
      const unsigned short* gb = zT + (size_t)(b0 + r) * Nn + k0 + g * 8;
      __builtin_amdgcn_global_load_lds((const __attribute__((address_space(1))) void*)ga,
                                       (__attribute__((address_space(3))) void*)(As + s * 8),
                                       16, 0, 0);
      __builtin_amdgcn_global_load_lds((const __attribute__((address_space(1))) void*)gb,
                                       (__attribute__((address_space(3))) void*)(Bs + s * 8),
                                       16, 0, 0);
    }
    __syncthreads();
#pragma unroll
    for (int kc = 0; kc < 2; ++kc) {
      bf16x8 afr[4], bfr[4];
#pragma unroll
      for (int mt = 0; mt < 4; ++mt) {
        int rA = wr * 64 + mt * 16 + l15;
        int g = kc * 4 + quad;
        int gl = g ^ (rA & 7);
        afr[mt] = *(const bf16x8*)(As + ((size_t)rA * 8 + gl) * 8);
      }
#pragma unroll
      for (int nt = 0; nt < 4; ++nt) {
        int rB = wc * 64 + nt * 16 + l15;
        int g = kc * 4 + quad;
        int gl = g ^ (rB & 7);
        bfr[nt] = *(const bf16x8*)(Bs + ((size_t)rB * 8 + gl) * 8);
      }
#pragma unroll
      for (int mt = 0; mt < 4; ++mt)
#pragma unroll
        for (int nt = 0; nt < 4; ++nt)
          acc[mt][nt] = __builtin_amdgcn_mfma_f32_16x16x32_bf16(afr[mt], bfr[nt],
                                                                acc[mt][nt], 0, 0, 0);
    }
    __syncthreads();
  }

  float* outp = covp + (size_t)p * 65536;
#pragma unroll
  for (int mt = 0; mt < 4; ++mt)
#pragma unroll
    for (int r = 0; r < 4; ++r) {
      int a = a0 + wr * 64 + mt * 16 + quad * 4 + r;
#pragma unroll
      for (int nt = 0; nt < 4; ++nt) {
        int b = b0 + wc * 64 + nt * 16 + l15;
        outp[(size_t)a * Ff + b] = acc[mt][nt][r];
      }
    }
}

// ---------- K3c: std from partial diagonals ----------
__global__ void k_diag(const float* __restrict__ covp, const float* __restrict__ colsum,
                       float* __restrict__ stdv) {
  int a = threadIdx.x;
  float m = colsum[a] * (1.f / 8192.f);
  float s = -8192.f * m * m;
#pragma unroll
  for (int p = 0; p < 16; ++p) s += covp[(size_t)p * 65536 + a * Ff + a];
  stdv[a] = sqrtf(s);
}

// ---------- K4: cor from partials ----------
__global__ void k_cor(const float* __restrict__ covp, const float* __restrict__ colsum,
                      const float* __restrict__ stdv, float* __restrict__ cor) {
  int idx = blockIdx.x * 256 + threadIdx.x;
  int a = idx >> 8, b = idx & 255;
  float c = 0.f;
  if (a != b) {
    float g = 0.f;
#pragma unroll
    for (int p = 0; p < 16; ++p) g += covp[(size_t)p * 65536 + idx];
    float cv = g - 8192.f * (colsum[a] * (1.f / 8192.f)) * (colsum[b] * (1.f / 8192.f));
    c = cv / (stdv[a] * stdv[b]);
    if (c != c) c = 0.f;                 // nan_to_num
    c = fminf(1.f, fmaxf(-1.f, c));      // clip
  }
  cor[idx] = c;
}

// ---------- K5: z2 = z + EPS*(w*zm)@cor, stored bf16 ----------
__global__ __launch_bounds__(256) void k_z2(const float* __restrict__ z,
    const float* __restrict__ colsum, const float* __restrict__ w,
    const float* __restrict__ cor, unsigned short* __restrict__ z2b) {
  __shared__ float Wl[32 * 256];
  int t = threadIdx.x;
  int row0 = blockIdx.x * 32;
  float mt = colsum[t] * (1.f / 8192.f);
  for (int rr = 0; rr < 32; ++rr) {
    int row = row0 + rr;
    Wl[rr * 256 + t] = w[row] * (z[(size_t)row * Ff + t] - mt);
  }
  __syncthreads();
  int tc = t & 63, tr = t >> 6;
  float acc[8][4];
#pragma unroll
  for (int i = 0; i < 8; ++i)
#pragma unroll
    for (int j = 0; j < 4; ++j) acc[i][j] = 0.f;
  const float* corc = cor + tc * 4;
  for (int k = 0; k < 256; ++k) {
    float4 c4 = *(const float4*)(corc + (size_t)k * 256);
#pragma unroll
    for (int rr = 0; rr < 8; ++rr) {
      float wv = Wl[(tr * 8 + rr) * 256 + k];
      acc[rr][0] = fmaf(wv, c4.x, acc[rr][0]);
      acc[rr][1] = fmaf(wv, c4.y, acc[rr][1]);
      acc[rr][2] = fmaf(wv, c4.z, acc[rr][2]);
      acc[rr][3] = fmaf(wv, c4.w, acc[rr][3]);
    }
  }
#pragma unroll
  for (int rr = 0; rr < 8; ++rr) {
    int row = row0 + tr * 8 + rr;
    float4 zv = *(const float4*)(z + (size_t)row * Ff + tc * 4);
    ushort4 o;
    o.x = f2b(zv.x + EPS_C * acc[rr][0]);
    o.y = f2b(zv.y + EPS_C * acc[rr][1]);
    o.z = f2b(zv.z + EPS_C * acc[rr][2]);
    o.w = f2b(zv.w + EPS_C * acc[rr][3]);
    *(ushort4*)(z2b + (size_t)row * Ff + tc * 4) = o;
  }
}

// ---------- K6: row norms of z2 ----------
__global__ void k_norms(const unsigned short* __restrict__ z2b, float* __restrict__ norms) {
  int lane = threadIdx.x & 63;
  int row = blockIdx.x * 4 + (threadIdx.x >> 6);
  ushort4 u = *((const ushort4*)(z2b + (size_t)row * Ff) + lane);
  float x0 = b2f(u.x), x1 = b2f(u.y), x2 = b2f(u.z), x3 = b2f(u.w);
  float s = x0 * x0 + x1 * x1 + x2 * x2 + x3 * x3;
#pragma unroll
  for (int m = 1; m < 64; m <<= 1) s += __shfl_xor(s, m);
  if (lane == 0) norms[row] = fmaxf(sqrtf(s), 1e-8f);
}

// ---------- K7: adjacency bitmask ----------
__global__ void k_adj(const int* __restrict__ ei, const int* __restrict__ ej,
                      unsigned int* __restrict__ adj) {
  int e = blockIdx.x * 256 + threadIdx.x;
  unsigned int i = (unsigned int)ei[e], j = (unsigned int)ej[e];
  size_t b1 = (size_t)i * Nn + j;
  size_t b2 = (size_t)j * Nn + i;
  atomicOr(&adj[b1 >> 5], 1u << (b1 & 31));
  atomicOr(&adj[b2 >> 5], 1u << (b2 & 31));
}

// ---------- K8: per-edge cosine, scatter by source ----------
__global__ void k_edge(const int* __restrict__ ei, const int* __restrict__ ej,
                       const unsigned short* __restrict__ z2b,
                       const float* __restrict__ norms,
                       float* __restrict__ scores, float* __restrict__ deg) {
  int lane = threadIdx.x & 63;
  int e = blockIdx.x * 4 + (threadIdx.x >> 6);
  int i = ei[e], j = ej[e];
  ushort4 ui = *((const ushort4*)(z2b + (size_t)i * Ff) + lane);
  ushort4 uj = *((const ushort4*)(z2b + (size_t)j * Ff) + lane);
  float d = b2f(ui.x) * b2f(uj.x) + b2f(ui.y) * b2f(uj.y) +
            b2f(ui.z) * b2f(uj.z) + b2f(ui.w) * b2f(uj.w);
#pragma unroll
  for (int m = 1; m < 64; m <<= 1) d += __shfl_xor(d, m);
  if (lane == 0) {
    float sim = d / (norms[i] * norms[j]);
    atomicAdd(&scores[i], sim);
    atomicAdd(&deg[i], 1.f);
  }
}

// ---------- K9: homophily reduce ----------
__global__ void k_homo(const float* __restrict__ scores, const float* __restrict__ deg,
                       double* __restrict__ hsum) {
  __shared__ float red[4];
  int n = blockIdx.x * 256 + threadIdx.x;
  float dg = deg[n];
  float v = scores[n] / (dg == 0.f ? 1.f : dg);
#pragma unroll
  for (int m = 1; m < 64; m <<= 1) v += __shfl_xor(v, m);
  int lane = threadIdx.x & 63, wv = threadIdx.x >> 6;
  if (lane == 0) red[wv] = v;
  __syncthreads();
  if (threadIdx.x == 0) atomicAdd(hsum, (double)(red[0] + red[1] + red[2] + red[3]));
}

// ---------- K10: fused penalty GEMM (z2 @ z2^T, masked thresholded sum) ----------
__global__ __launch_bounds__(256, 2) void k_penalty(const unsigned short* __restrict__ z2b,
    const unsigned int* __restrict__ adj, double* __restrict__ psum) {
  int bc = blockIdx.x, br = blockIdx.y;
  if (br > bc) return;                       // symmetry: upper-triangular tiles only
  __shared__ __align__(16) unsigned short As[128 * 64];
  __shared__ __align__(16) unsigned short Bs[128 * 64];
  __shared__ float red[4];
  int t = threadIdx.x;
  int lane = t & 63;
  int wv = t >> 6;
  int wr = wv >> 1, wc = wv & 1;             // 2x2 waves, each 64x64
  int quad = lane >> 4;
  int l15 = lane & 15;
  int arow0 = br * 128, brow0 = bc * 128;

  f32x4 acc[4][4];
#pragma unroll
  for (int i = 0; i < 4; ++i)
#pragma unroll
    for (int j = 0; j < 4; ++j) acc[i][j] = (f32x4){0.f, 0.f, 0.f, 0.f};

  for (int kk = 0; kk < 4; ++kk) {
    int k0 = kk * 64;
#pragma unroll
    for (int it = 0; it < 4; ++it) {
      int s = it * 256 + t;                  // LDS granule index (16B granules)
      int r = s >> 3;
      int g = (s & 7) ^ (r & 7);             // global k-granule stored at this slot
      const unsigned short* ga = z2b + (size_t)(arow0 + r) * Ff + k0 + g * 8;
      const unsigned short* gb = z2b + (size_t)(brow0 + r) * Ff + k0 + g * 8;
      __builtin_amdgcn_global_load_lds((const __attribute__((address_space(1))) void*)ga,
                                       (__attribute__((address_space(3))) void*)(As + s * 8),
                                       16, 0, 0);
      __builtin_amdgcn_global_load_lds((const __attribute__((address_space(1))) void*)gb,
                                       (__attribute__((address_space(3))) void*)(Bs + s * 8),
                                       16, 0, 0);
    }
    __syncthreads();
#pragma unroll
    for (int kc = 0; kc < 2; ++kc) {
      bf16x8 afr[4], bfr[4];
#pragma unroll
      for (int mt = 0; mt < 4; ++mt) {
        int rA = wr * 64 + mt * 16 + l15;
        int g = kc * 4 + quad;
        int gl = g ^ (rA & 7);
        afr[mt] = *(const bf16x8*)(As + ((size_t)rA * 8 + gl) * 8);
      }
#pragma unroll
      for (int nt = 0; nt < 4; ++nt) {
        int rB = wc * 64 + nt * 16 + l15;
        int g = kc * 4 + quad;
        int gl = g ^ (rB & 7);
        bfr[nt] = *(const bf16x8*)(Bs + ((size_t)rB * 8 + gl) * 8);
      }
#pragma unroll
      for (int mt = 0; mt < 4; ++mt)
#pragma unroll
        for (int nt = 0; nt < 4; ++nt)
          acc[mt][nt] = __builtin_amdgcn_mfma_f32_16x16x32_bf16(afr[mt], bfr[nt],
                                                                acc[mt][nt], 0, 0, 0);
    }
    __syncthreads();
  }

  float local = 0.f;
  int a_base = arow0 + wr * 64;
  int b_base = brow0 + wc * 64;              // 64-aligned
#pragma unroll
  for (int mt = 0; mt < 4; ++mt) {
#pragma unroll
    for (int r = 0; r < 4; ++r) {
      int a = a_base + mt * 16 + quad * 4 + r;
      uint64_t bits = *(const uint64_t*)(adj + (size_t)a * 256 + (b_base >> 5));
#pragma unroll
      for (int nt = 0; nt < 4; ++nt) {
        float v = acc[mt][nt][r];
        int boff = nt * 16 + l15;
        bool conn = (bits >> boff) & 1ull;
        float wgt;
        if (br != bc) wgt = 2.f;
        else {
          int b = b_base + boff;
          wgt = (a < b) ? 2.f : (a == b ? 1.f : 0.f);
        }
        if (!conn && v > THRESH) local += wgt * v;
      }
    }
  }
#pragma unroll
  for (int m = 1; m < 64; m <<= 1) local += __shfl_xor(local, m);
  if (lane == 0) red[wv] = local;
  __syncthreads();
  if (t == 0) atomicAdd(psum, (double)(red[0] + red[1] + red[2] + red[3]));
}

// ---------- K11: combine ----------
__global__ void k_final(const double* __restrict__ hsum, const double* __restrict__ psum,
                        float* __restrict__ out) {
  if (threadIdx.x == 0) {
    double h = -(*hsum) / 8192.0;
    double p = (*psum) / (8192.0 * 8192.0);
    out[0] = (float)(h + p);
  }
}

extern "C" void kernel_launch(void* const* d_in, const int* in_sizes, int n_in,
                              void* d_out, int out_size, void* d_ws, size_t ws_size,
                              hipStream_t stream) {
  const float* z = (const float*)d_in[0];
  // d_in[1] = x_hat (unused by the reference)
  const int* ei = (const int*)d_in[2];
  const int* ej = ei + Ee;
  const int* k2u = (const int*)d_in[3];
  const int* u2k = (const int*)d_in[4];

  char* ws = (char*)d_ws;
  // zeroed region: [0, ZERO_BYTES)
  unsigned int* adj = (unsigned int*)(ws);               // 8 MiB
  float* colsum     = (float*)(ws + 8388608);            // 1 KiB
  float* scores     = (float*)(ws + 8389632);            // 32 KiB
  float* deg        = (float*)(ws + 8422400);            // 32 KiB
  double* psum      = (double*)(ws + 8455168);
  double* hsum      = (double*)(ws + 8455176);
  const size_t ZERO_BYTES = 8455184;
  // non-zeroed scratch
  float* covp       = (float*)(ws + 8455296);            // 16 x 256 KiB = 4 MiB
  unsigned short* zT  = (unsigned short*)(ws + 12649600); // 4 MiB
  unsigned short* z2b = (unsigned short*)(ws + 16843904); // 4 MiB
  float* cor        = (float*)(ws + 21038208);           // 256 KiB
  float* w          = (float*)(ws + 21300352);           // 32 KiB
  float* norms      = (float*)(ws + 21333120);           // 32 KiB
  float* stdv       = (float*)(ws + 21365888);           // 1 KiB

  hipMemsetAsync(d_ws, 0, ZERO_BYTES, stream);
  k_colsum<<<64, 256, 0, stream>>>(z, colsum);
  k_w<<<32, 256, 0, stream>>>(k2u, u2k, w);
  k_adj<<<1024, 256, 0, stream>>>(ei, ej, adj);
  k_transpose<<<dim3(128, 4), 256, 0, stream>>>(z, zT);
  k_covg<<<dim3(2, 2, 16), 256, 0, stream>>>(zT, covp);
  k_diag<<<1, 256, 0, stream>>>(covp, colsum, stdv);
  k_cor<<<256, 256, 0, stream>>>(covp, colsum, stdv, cor);
  k_z2<<<256, 256, 0, stream>>>(z, colsum, w, cor, z2b);
  k_norms<<<2048, 256, 0, stream>>>(z2b, norms);
  k_edge<<<65536, 256, 0, stream>>>(ei, ej, z2b, norms, scores, deg);
  k_homo<<<32, 256, 0, stream>>>(scores, deg, hsum);
  k_penalty<<<dim3(64, 64), 256, 0, stream>>>(z2b, adj, psum);
  k_final<<<1, 64, 0, stream>>>(hsum, psum, (float*)d_out);
}

// Round 4
// 232.574 us; speedup vs baseline: 1.7140x; 1.1132x over previous
//
#include <hip/hip_runtime.h>
#include <stdint.h>

#define EPS_C 0.01f
#define THRESH 0.8f

constexpr int Nn = 8192;
constexpr int Ff = 256;
constexpr int Ee = 262144;

__device__ __forceinline__ float b2f(unsigned short u) {
  union { uint32_t i; float f; } v; v.i = ((uint32_t)u) << 16; return v.f;
}
__device__ __forceinline__ unsigned short f2b(float f) {
  union { uint32_t i; float f; } v; v.f = f;
  uint32_t r = v.i + 0x7FFFu + ((v.i >> 16) & 1u);
  return (unsigned short)(r >> 16);
}

// ---------- K1: column sums of z (f32) ----------
__global__ void k_colsum(const float* __restrict__ z, float* __restrict__ colsum) {
  int t = threadIdx.x;              // column 0..255
  int r0 = blockIdx.x * 128;        // 64 blocks * 128 rows
  float acc = 0.f;
#pragma unroll 8
  for (int r = 0; r < 128; ++r)
    acc += z[(size_t)(r0 + r) * Ff + t];
  atomicAdd(&colsum[t], acc);
}

// ---------- K2: per-node weight w ----------
__global__ void k_w(const int* __restrict__ k2u, const int* __restrict__ u2k,
                    float* __restrict__ w) {
  int n = blockIdx.x * 256 + threadIdx.x;
  w[n] = powf(0.9f, (float)k2u[n]) + 1.f - powf(0.9f, (float)u2k[n]);
}

// ---------- K3a: transpose+quantize z -> zT bf16 [256][8192] ----------
__global__ void k_transpose(const float* __restrict__ z, unsigned short* __restrict__ zT) {
  __shared__ float Ls[64][65];
  int n0 = blockIdx.x * 64;
  int c0 = blockIdx.y * 64;
  int t = threadIdx.x;
  int r = t >> 4;        // 0..15
  int cq = t & 15;       // 0..15
#pragma unroll
  for (int i = 0; i < 4; ++i) {
    int row = r + 16 * i;
    float4 v = *(const float4*)(z + (size_t)(n0 + row) * Ff + c0 + cq * 4);
    Ls[row][cq * 4 + 0] = v.x;
    Ls[row][cq * 4 + 1] = v.y;
    Ls[row][cq * 4 + 2] = v.z;
    Ls[row][cq * 4 + 3] = v.w;
  }
  __syncthreads();
  int cr = t >> 4;       // row (feature) within tile
  int nq = t & 15;       // n-quad
#pragma unroll
  for (int i = 0; i < 4; ++i) {
    int c = cr + 16 * i;
    ushort4 o;
    o.x = f2b(Ls[nq * 4 + 0][c]);
    o.y = f2b(Ls[nq * 4 + 1][c]);
    o.z = f2b(Ls[nq * 4 + 2][c]);
    o.w = f2b(Ls[nq * 4 + 3][c]);
    *(ushort4*)(zT + (size_t)(c0 + c) * Nn + n0 + nq * 4) = o;
  }
}

// ---------- K3b: G = zT @ zT^T via MFMA, split-K=16 partials ----------
typedef __bf16 bf16x8 __attribute__((ext_vector_type(8)));
typedef float f32x4 __attribute__((ext_vector_type(4)));

__global__ __launch_bounds__(256, 2) void k_covg(const unsigned short* __restrict__ zT,
                                                 float* __restrict__ covp) {
  int bx = blockIdx.x, by = blockIdx.y, p = blockIdx.z;
  __shared__ __align__(16) unsigned short As[128 * 64];
  __shared__ __align__(16) unsigned short Bs[128 * 64];
  int t = threadIdx.x;
  int lane = t & 63, wv = t >> 6;
  int wr = wv >> 1, wc = wv & 1;
  int quad = lane >> 4, l15 = lane & 15;
  int a0 = by * 128, b0 = bx * 128;

  f32x4 acc[4][4];
#pragma unroll
  for (int i = 0; i < 4; ++i)
#pragma unroll
    for (int j = 0; j < 4; ++j) acc[i][j] = (f32x4){0.f, 0.f, 0.f, 0.f};

  for (int kk = 0; kk < 8; ++kk) {
    int k0 = p * 512 + kk * 64;
#pragma unroll
    for (int it = 0; it < 4; ++it) {
      int s = it * 256 + t;
      int r = s >> 3;
      int g = (s & 7) ^ (r & 7);
      const unsigned short* ga = zT + (size_t)(a0 + r) * Nn + k0 + g * 8;
      const unsigned short* gb = zT + (size_t)(b0 + r) * Nn + k0 + g * 8;
      __builtin_amdgcn_global_load_lds((const __attribute__((address_space(1))) void*)ga,
                                       (__attribute__((address_space(3))) void*)(As + s * 8),
                                       16, 0, 0);
      __builtin_amdgcn_global_load_lds((const __attribute__((address_space(1))) void*)gb,
                                       (__attribute__((address_space(3))) void*)(Bs + s * 8),
                                       16, 0, 0);
    }
    __syncthreads();
#pragma unroll
    for (int kc = 0; kc < 2; ++kc) {
      bf16x8 afr[4], bfr[4];
#pragma unroll
      for (int mt = 0; mt < 4; ++mt) {
        int rA = wr * 64 + mt * 16 + l15;
        int g = kc * 4 + quad;
        int gl = g ^ (rA & 7);
        afr[mt] = *(const bf16x8*)(As + ((size_t)rA * 8 + gl) * 8);
      }
#pragma unroll
      for (int nt = 0; nt < 4; ++nt) {
        int rB = wc * 64 + nt * 16 + l15;
        int g = kc * 4 + quad;
        int gl = g ^ (rB & 7);
        bfr[nt] = *(const bf16x8*)(Bs + ((size_t)rB * 8 + gl) * 8);
      }
#pragma unroll
      for (int mt = 0; mt < 4; ++mt)
#pragma unroll
        for (int nt = 0; nt < 4; ++nt)
          acc[mt][nt] = __builtin_amdgcn_mfma_f32_16x16x32_bf16(afr[mt], bfr[nt],
                                                                acc[mt][nt], 0, 0, 0);
    }
    __syncthreads();
  }

  float* outp = covp + (size_t)p * 65536;
#pragma unroll
  for (int mt = 0; mt < 4; ++mt)
#pragma unroll
    for (int r = 0; r < 4; ++r) {
      int a = a0 + wr * 64 + mt * 16 + quad * 4 + r;
#pragma unroll
      for (int nt = 0; nt < 4; ++nt) {
        int b = b0 + wc * 64 + nt * 16 + l15;
        outp[(size_t)a * Ff + b] = acc[mt][nt][r];
      }
    }
}

// ---------- K3c: std from partial diagonals ----------
__global__ void k_diag(const float* __restrict__ covp, const float* __restrict__ colsum,
                       float* __restrict__ stdv) {
  int a = threadIdx.x;
  float m = colsum[a] * (1.f / 8192.f);
  float s = -8192.f * m * m;
#pragma unroll
  for (int p = 0; p < 16; ++p) s += covp[(size_t)p * 65536 + a * Ff + a];
  stdv[a] = sqrtf(s);
}

// ---------- K4: cor from partials ----------
__global__ void k_cor(const float* __restrict__ covp, const float* __restrict__ colsum,
                      const float* __restrict__ stdv, float* __restrict__ cor) {
  int idx = blockIdx.x * 256 + threadIdx.x;
  int a = idx >> 8, b = idx & 255;
  float c = 0.f;
  if (a != b) {
    float g = 0.f;
#pragma unroll
    for (int p = 0; p < 16; ++p) g += covp[(size_t)p * 65536 + idx];
    float cv = g - 8192.f * (colsum[a] * (1.f / 8192.f)) * (colsum[b] * (1.f / 8192.f));
    c = cv / (stdv[a] * stdv[b]);
    if (c != c) c = 0.f;                 // nan_to_num
    c = fminf(1.f, fmaxf(-1.f, c));      // clip
  }
  cor[idx] = c;
}

// ---------- K5: z2 = z + EPS*(w*zm)@cor, stored bf16; row norms fused ----------
__global__ __launch_bounds__(256) void k_z2(const float* __restrict__ z,
    const float* __restrict__ colsum, const float* __restrict__ w,
    const float* __restrict__ cor, unsigned short* __restrict__ z2b,
    float* __restrict__ norms) {
  __shared__ float Wl[32 * 256];
  int t = threadIdx.x;
  int row0 = blockIdx.x * 32;
  float mt = colsum[t] * (1.f / 8192.f);
  for (int rr = 0; rr < 32; ++rr) {
    int row = row0 + rr;
    Wl[rr * 256 + t] = w[row] * (z[(size_t)row * Ff + t] - mt);
  }
  __syncthreads();
  int tc = t & 63, tr = t >> 6;   // wave tr owns rows [tr*8, tr*8+8); lane == tc
  float acc[8][4];
#pragma unroll
  for (int i = 0; i < 8; ++i)
#pragma unroll
    for (int j = 0; j < 4; ++j) acc[i][j] = 0.f;
  const float* corc = cor + tc * 4;
  for (int k = 0; k < 256; ++k) {
    float4 c4 = *(const float4*)(corc + (size_t)k * 256);
#pragma unroll
    for (int rr = 0; rr < 8; ++rr) {
      float wv = Wl[(tr * 8 + rr) * 256 + k];
      acc[rr][0] = fmaf(wv, c4.x, acc[rr][0]);
      acc[rr][1] = fmaf(wv, c4.y, acc[rr][1]);
      acc[rr][2] = fmaf(wv, c4.z, acc[rr][2]);
      acc[rr][3] = fmaf(wv, c4.w, acc[rr][3]);
    }
  }
#pragma unroll
  for (int rr = 0; rr < 8; ++rr) {
    int row = row0 + tr * 8 + rr;
    float4 zv = *(const float4*)(z + (size_t)row * Ff + tc * 4);
    float x0 = zv.x + EPS_C * acc[rr][0];
    float x1 = zv.y + EPS_C * acc[rr][1];
    float x2 = zv.z + EPS_C * acc[rr][2];
    float x3 = zv.w + EPS_C * acc[rr][3];
    ushort4 o;
    o.x = f2b(x0); o.y = f2b(x1); o.z = f2b(x2); o.w = f2b(x3);
    *(ushort4*)(z2b + (size_t)row * Ff + tc * 4) = o;
    // fused row-norm: reduce x^2 across the 64 lanes of this wave
    float s = x0 * x0 + x1 * x1 + x2 * x2 + x3 * x3;
#pragma unroll
    for (int m = 1; m < 64; m <<= 1) s += __shfl_xor(s, m);
    if (tc == 0) norms[row] = fmaxf(sqrtf(s), 1e-8f);
  }
}

// ---------- K7: adjacency bitmask ----------
__global__ void k_adj(const int* __restrict__ ei, const int* __restrict__ ej,
                      unsigned int* __restrict__ adj) {
  int e = blockIdx.x * 256 + threadIdx.x;
  unsigned int i = (unsigned int)ei[e], j = (unsigned int)ej[e];
  size_t b1 = (size_t)i * Nn + j;
  size_t b2 = (size_t)j * Nn + i;
  atomicOr(&adj[b1 >> 5], 1u << (b1 & 31));
  atomicOr(&adj[b2 >> 5], 1u << (b2 & 31));
}

// ---------- K8: per-edge cosine, batched: 2048 blocks, 2 edges/wave/iter ----------
__global__ __launch_bounds__(256) void k_edge(const int* __restrict__ ei,
                       const int* __restrict__ ej,
                       const unsigned short* __restrict__ z2b,
                       const float* __restrict__ norms,
                       float* __restrict__ scores, float* __restrict__ deg) {
  int t = threadIdx.x;
  int wv = t >> 6, lane = t & 63;
  int half = lane >> 5;                 // which of the 2 edges this iteration
  int l32 = lane & 31;                  // 8 bf16 elems per lane: l32*8 .. l32*8+7
  int gw = blockIdx.x * 4 + wv;         // global wave id, 0..8191
  int ebase = gw * 32;                  // 32 edges per wave
#pragma unroll 2
  for (int it = 0; it < 16; ++it) {
    int e = ebase + it * 2 + half;
    int i = ei[e], j = ej[e];
    uint4 ua = *(const uint4*)(z2b + (size_t)i * Ff + l32 * 8);
    uint4 ub = *(const uint4*)(z2b + (size_t)j * Ff + l32 * 8);
    float d = 0.f;
    const uint32_t* pa = (const uint32_t*)&ua;
    const uint32_t* pb = (const uint32_t*)&ub;
#pragma unroll
    for (int q = 0; q < 4; ++q) {
      union { uint32_t u; float f; } alo, ahi, blo, bhi;
      alo.u = pa[q] << 16;  ahi.u = pa[q] & 0xffff0000u;
      blo.u = pb[q] << 16;  bhi.u = pb[q] & 0xffff0000u;
      d = fmaf(alo.f, blo.f, d);
      d = fmaf(ahi.f, bhi.f, d);
    }
#pragma unroll
    for (int m = 1; m < 32; m <<= 1) d += __shfl_xor(d, m);
    if (l32 == 0) {
      float sim = d / (norms[i] * norms[j]);
      atomicAdd(&scores[i], sim);
      atomicAdd(&deg[i], 1.f);
    }
  }
}

// ---------- K9: homophily reduce ----------
__global__ void k_homo(const float* __restrict__ scores, const float* __restrict__ deg,
                       double* __restrict__ hsum) {
  __shared__ float red[4];
  int n = blockIdx.x * 256 + threadIdx.x;
  float dg = deg[n];
  float v = scores[n] / (dg == 0.f ? 1.f : dg);
#pragma unroll
  for (int m = 1; m < 64; m <<= 1) v += __shfl_xor(v, m);
  int lane = threadIdx.x & 63, wv = threadIdx.x >> 6;
  if (lane == 0) red[wv] = v;
  __syncthreads();
  if (threadIdx.x == 0) atomicAdd(hsum, (double)(red[0] + red[1] + red[2] + red[3]));
}

// ---------- K10: fused penalty GEMM (z2 @ z2^T, masked thresholded sum) ----------
__global__ __launch_bounds__(256, 2) void k_penalty(const unsigned short* __restrict__ z2b,
    const unsigned int* __restrict__ adj, double* __restrict__ psum) {
  int bc = blockIdx.x, br = blockIdx.y;
  if (br > bc) return;                       // symmetry: upper-triangular tiles only
  __shared__ __align__(16) unsigned short As[128 * 64];
  __shared__ __align__(16) unsigned short Bs[128 * 64];
  __shared__ float red[4];
  int t = threadIdx.x;
  int lane = t & 63;
  int wv = t >> 6;
  int wr = wv >> 1, wc = wv & 1;             // 2x2 waves, each 64x64
  int quad = lane >> 4;
  int l15 = lane & 15;
  int arow0 = br * 128, brow0 = bc * 128;

  f32x4 acc[4][4];
#pragma unroll
  for (int i = 0; i < 4; ++i)
#pragma unroll
    for (int j = 0; j < 4; ++j) acc[i][j] = (f32x4){0.f, 0.f, 0.f, 0.f};

  for (int kk = 0; kk < 4; ++kk) {
    int k0 = kk * 64;
#pragma unroll
    for (int it = 0; it < 4; ++it) {
      int s = it * 256 + t;                  // LDS granule index (16B granules)
      int r = s >> 3;
      int g = (s & 7) ^ (r & 7);             // global k-granule stored at this slot
      const unsigned short* ga = z2b + (size_t)(arow0 + r) * Ff + k0 + g * 8;
      const unsigned short* gb = z2b + (size_t)(brow0 + r) * Ff + k0 + g * 8;
      __builtin_amdgcn_global_load_lds((const __attribute__((address_space(1))) void*)ga,
                                       (__attribute__((address_space(3))) void*)(As + s * 8),
                                       16, 0, 0);
      __builtin_amdgcn_global_load_lds((const __attribute__((address_space(1))) void*)gb,
                                       (__attribute__((address_space(3))) void*)(Bs + s * 8),
                                       16, 0, 0);
    }
    __syncthreads();
#pragma unroll
    for (int kc = 0; kc < 2; ++kc) {
      bf16x8 afr[4], bfr[4];
#pragma unroll
      for (int mt = 0; mt < 4; ++mt) {
        int rA = wr * 64 + mt * 16 + l15;
        int g = kc * 4 + quad;
        int gl = g ^ (rA & 7);
        afr[mt] = *(const bf16x8*)(As + ((size_t)rA * 8 + gl) * 8);
      }
#pragma unroll
      for (int nt = 0; nt < 4; ++nt) {
        int rB = wc * 64 + nt * 16 + l15;
        int g = kc * 4 + quad;
        int gl = g ^ (rB & 7);
        bfr[nt] = *(const bf16x8*)(Bs + ((size_t)rB * 8 + gl) * 8);
      }
#pragma unroll
      for (int mt = 0; mt < 4; ++mt)
#pragma unroll
        for (int nt = 0; nt < 4; ++nt)
          acc[mt][nt] = __builtin_amdgcn_mfma_f32_16x16x32_bf16(afr[mt], bfr[nt],
                                                                acc[mt][nt], 0, 0, 0);
    }
    __syncthreads();
  }

  float local = 0.f;
  int a_base = arow0 + wr * 64;
  int b_base = brow0 + wc * 64;              // 64-aligned
#pragma unroll
  for (int mt = 0; mt < 4; ++mt) {
#pragma unroll
    for (int r = 0; r < 4; ++r) {
      int a = a_base + mt * 16 + quad * 4 + r;
      uint64_t bits = *(const uint64_t*)(adj + (size_t)a * 256 + (b_base >> 5));
#pragma unroll
      for (int nt = 0; nt < 4; ++nt) {
        float v = acc[mt][nt][r];
        int boff = nt * 16 + l15;
        bool conn = (bits >> boff) & 1ull;
        float wgt;
        if (br != bc) wgt = 2.f;
        else {
          int b = b_base + boff;
          wgt = (a < b) ? 2.f : (a == b ? 1.f : 0.f);
        }
        if (!conn && v > THRESH) local += wgt * v;
      }
    }
  }
#pragma unroll
  for (int m = 1; m < 64; m <<= 1) local += __shfl_xor(local, m);
  if (lane == 0) red[wv] = local;
  __syncthreads();
  if (t == 0) atomicAdd(psum, (double)(red[0] + red[1] + red[2] + red[3]));
}

// ---------- K11: combine ----------
__global__ void k_final(const double* __restrict__ hsum, const double* __restrict__ psum,
                        float* __restrict__ out) {
  if (threadIdx.x == 0) {
    double h = -(*hsum) / 8192.0;
    double p = (*psum) / (8192.0 * 8192.0);
    out[0] = (float)(h + p);
  }
}

extern "C" void kernel_launch(void* const* d_in, const int* in_sizes, int n_in,
                              void* d_out, int out_size, void* d_ws, size_t ws_size,
                              hipStream_t stream) {
  const float* z = (const float*)d_in[0];
  // d_in[1] = x_hat (unused by the reference)
  const int* ei = (const int*)d_in[2];
  const int* ej = ei + Ee;
  const int* k2u = (const int*)d_in[3];
  const int* u2k = (const int*)d_in[4];

  char* ws = (char*)d_ws;
  // zeroed region: [0, ZERO_BYTES)
  unsigned int* adj = (unsigned int*)(ws);               // 8 MiB
  float* colsum     = (float*)(ws + 8388608);            // 1 KiB
  float* scores     = (float*)(ws + 8389632);            // 32 KiB
  float* deg        = (float*)(ws + 8422400);            // 32 KiB
  double* psum      = (double*)(ws + 8455168);
  double* hsum      = (double*)(ws + 8455176);
  const size_t ZERO_BYTES = 8455184;
  // non-zeroed scratch
  float* covp       = (float*)(ws + 8455296);            // 16 x 256 KiB = 4 MiB
  unsigned short* zT  = (unsigned short*)(ws + 12649600); // 4 MiB
  unsigned short* z2b = (unsigned short*)(ws + 16843904); // 4 MiB
  float* cor        = (float*)(ws + 21038208);           // 256 KiB
  float* w          = (float*)(ws + 21300352);           // 32 KiB
  float* norms      = (float*)(ws + 21333120);           // 32 KiB
  float* stdv       = (float*)(ws + 21365888);           // 1 KiB

  hipMemsetAsync(d_ws, 0, ZERO_BYTES, stream);
  k_colsum<<<64, 256, 0, stream>>>(z, colsum);
  k_w<<<32, 256, 0, stream>>>(k2u, u2k, w);
  k_adj<<<1024, 256, 0, stream>>>(ei, ej, adj);
  k_transpose<<<dim3(128, 4), 256, 0, stream>>>(z, zT);
  k_covg<<<dim3(2, 2, 16), 256, 0, stream>>>(zT, covp);
  k_diag<<<1, 256, 0, stream>>>(covp, colsum, stdv);
  k_cor<<<256, 256, 0, stream>>>(covp, colsum, stdv, cor);
  k_z2<<<256, 256, 0, stream>>>(z, colsum, w, cor, z2b, norms);
  k_edge<<<2048, 256, 0, stream>>>(ei, ej, z2b, norms, scores, deg);
  k_homo<<<32, 256, 0, stream>>>(scores, deg, hsum);
  k_penalty<<<dim3(64, 64), 256, 0, stream>>>(z2b, adj, psum);
  k_final<<<1, 64, 0, stream>>>(hsum, psum, (float*)d_out);
}

// Round 5
// 224.555 us; speedup vs baseline: 1.7753x; 1.0357x over previous
//
#include <hip/hip_runtime.h>
#include <stdint.h>
#include <math.h>

#define EPS_C 0.01f
#define THRESH 0.8f

constexpr int Nn = 8192;
constexpr int Ff = 256;
constexpr int Ee = 262144;

__device__ __forceinline__ float b2f(unsigned short u) {
  union { uint32_t i; float f; } v; v.i = ((uint32_t)u) << 16; return v.f;
}
__device__ __forceinline__ unsigned short f2b(float f) {
  union { uint32_t i; float f; } v; v.f = f;
  uint32_t r = v.i + 0x7FFFu + ((v.i >> 16) & 1u);
  return (unsigned short)(r >> 16);
}

typedef __bf16 bf16x8 __attribute__((ext_vector_type(8)));
typedef float f32x4 __attribute__((ext_vector_type(4)));

// ---------- K3a: transpose+quantize z -> zT bf16 [256][8192]; colsum fused ----------
__global__ void k_transpose(const float* __restrict__ z, unsigned short* __restrict__ zT,
                            float* __restrict__ colsum) {
  __shared__ float Ls[64][65];
  int n0 = blockIdx.x * 64;
  int c0 = blockIdx.y * 64;
  int t = threadIdx.x;
  int r = t >> 4;        // 0..15
  int cq = t & 15;       // 0..15
#pragma unroll
  for (int i = 0; i < 4; ++i) {
    int row = r + 16 * i;
    float4 v = *(const float4*)(z + (size_t)(n0 + row) * Ff + c0 + cq * 4);
    Ls[row][cq * 4 + 0] = v.x;
    Ls[row][cq * 4 + 1] = v.y;
    Ls[row][cq * 4 + 2] = v.z;
    Ls[row][cq * 4 + 3] = v.w;
  }
  __syncthreads();
  // fused column-sum partial (64 rows of this tile)
  if (t < 64) {
    float s = 0.f;
#pragma unroll
    for (int rr = 0; rr < 64; ++rr) s += Ls[rr][t];
    atomicAdd(&colsum[c0 + t], s);
  }
  int cr = t >> 4;       // feature within tile
  int nq = t & 15;       // n-quad
#pragma unroll
  for (int i = 0; i < 4; ++i) {
    int c = cr + 16 * i;
    ushort4 o;
    o.x = f2b(Ls[nq * 4 + 0][c]);
    o.y = f2b(Ls[nq * 4 + 1][c]);
    o.z = f2b(Ls[nq * 4 + 2][c]);
    o.w = f2b(Ls[nq * 4 + 3][c]);
    *(ushort4*)(zT + (size_t)(c0 + c) * Nn + n0 + nq * 4) = o;
  }
}

// ---------- K3b: G = zT @ zT^T via MFMA, split-K=16 partials ----------
__global__ __launch_bounds__(256, 2) void k_covg(const unsigned short* __restrict__ zT,
                                                 float* __restrict__ covp) {
  int bx = blockIdx.x, by = blockIdx.y, p = blockIdx.z;
  __shared__ __align__(16) unsigned short As[128 * 64];
  __shared__ __align__(16) unsigned short Bs[128 * 64];
  int t = threadIdx.x;
  int lane = t & 63, wv = t >> 6;
  int wr = wv >> 1, wc = wv & 1;
  int quad = lane >> 4, l15 = lane & 15;
  int a0 = by * 128, b0 = bx * 128;

  f32x4 acc[4][4];
#pragma unroll
  for (int i = 0; i < 4; ++i)
#pragma unroll
    for (int j = 0; j < 4; ++j) acc[i][j] = (f32x4){0.f, 0.f, 0.f, 0.f};

  for (int kk = 0; kk < 8; ++kk) {
    int k0 = p * 512 + kk * 64;
#pragma unroll
    for (int it = 0; it < 4; ++it) {
      int s = it * 256 + t;
      int r = s >> 3;
      int g = (s & 7) ^ (r & 7);
      const unsigned short* ga = zT + (size_t)(a0 + r) * Nn + k0 + g * 8;
      const unsigned short* gb = zT + (size_t)(b0 + r) * Nn + k0 + g * 8;
      __builtin_amdgcn_global_load_lds((const __attribute__((address_space(1))) void*)ga,
                                       (__attribute__((address_space(3))) void*)(As + s * 8),
                                       16, 0, 0);
      __builtin_amdgcn_global_load_lds((const __attribute__((address_space(1))) void*)gb,
                                       (__attribute__((address_space(3))) void*)(Bs + s * 8),
                                       16, 0, 0);
    }
    __syncthreads();
#pragma unroll
    for (int kc = 0; kc < 2; ++kc) {
      bf16x8 afr[4], bfr[4];
#pragma unroll
      for (int mt = 0; mt < 4; ++mt) {
        int rA = wr * 64 + mt * 16 + l15;
        int g = kc * 4 + quad;
        int gl = g ^ (rA & 7);
        afr[mt] = *(const bf16x8*)(As + ((size_t)rA * 8 + gl) * 8);
      }
#pragma unroll
      for (int nt = 0; nt < 4; ++nt) {
        int rB = wc * 64 + nt * 16 + l15;
        int g = kc * 4 + quad;
        int gl = g ^ (rB & 7);
        bfr[nt] = *(const bf16x8*)(Bs + ((size_t)rB * 8 + gl) * 8);
      }
#pragma unroll
      for (int mt = 0; mt < 4; ++mt)
#pragma unroll
        for (int nt = 0; nt < 4; ++nt)
          acc[mt][nt] = __builtin_amdgcn_mfma_f32_16x16x32_bf16(afr[mt], bfr[nt],
                                                                acc[mt][nt], 0, 0, 0);
    }
    __syncthreads();
  }

  float* outp = covp + (size_t)p * 65536;
#pragma unroll
  for (int mt = 0; mt < 4; ++mt)
#pragma unroll
    for (int r = 0; r < 4; ++r) {
      int a = a0 + wr * 64 + mt * 16 + quad * 4 + r;
#pragma unroll
      for (int nt = 0; nt < 4; ++nt) {
        int b = b0 + wc * 64 + nt * 16 + l15;
        outp[(size_t)a * Ff + b] = acc[mt][nt][r];
      }
    }
}

// ---------- K4: cor from partials (diag/std fused) ----------
__global__ void k_cor(const float* __restrict__ covp, const float* __restrict__ colsum,
                      float* __restrict__ cor) {
  __shared__ float sd[256];
  int a = blockIdx.x, b = threadIdx.x;
  float mb = colsum[b] * (1.f / 8192.f);
  float gb = 0.f;
#pragma unroll
  for (int p = 0; p < 16; ++p) gb += covp[(size_t)p * 65536 + b * 257];
  float sb = sqrtf(gb - 8192.f * mb * mb);
  sd[b] = sb;
  float g = 0.f;
#pragma unroll
  for (int p = 0; p < 16; ++p) g += covp[(size_t)p * 65536 + a * Ff + b];
  __syncthreads();
  float c = 0.f;
  if (a != b) {
    float ma = colsum[a] * (1.f / 8192.f);
    float cv = g - 8192.f * ma * mb;
    c = cv / (sd[a] * sb);
    if (c != c) c = 0.f;                 // nan_to_num
    c = fminf(1.f, fmaxf(-1.f, c));      // clip
  }
  cor[a * Ff + b] = c;
}

// ---------- K5: z2 = z + EPS*(w*zm)@cor, bf16; w + row norms fused ----------
__global__ __launch_bounds__(256) void k_z2(const float* __restrict__ z,
    const float* __restrict__ colsum, const int* __restrict__ k2u,
    const int* __restrict__ u2k, const float* __restrict__ cor,
    unsigned short* __restrict__ z2b, float* __restrict__ norms) {
  __shared__ float Wl[32 * 256];
  __shared__ float ws_[32];
  int t = threadIdx.x;
  int row0 = blockIdx.x * 32;
  if (t < 32) {
    int row = row0 + t;
    ws_[t] = powf(0.9f, (float)k2u[row]) + 1.f - powf(0.9f, (float)u2k[row]);
  }
  __syncthreads();
  float mt = colsum[t] * (1.f / 8192.f);
  for (int rr = 0; rr < 32; ++rr) {
    int row = row0 + rr;
    Wl[rr * 256 + t] = ws_[rr] * (z[(size_t)row * Ff + t] - mt);
  }
  __syncthreads();
  int tc = t & 63, tr = t >> 6;   // wave tr owns rows [tr*8, tr*8+8); lane == tc
  float acc[8][4];
#pragma unroll
  for (int i = 0; i < 8; ++i)
#pragma unroll
    for (int j = 0; j < 4; ++j) acc[i][j] = 0.f;
  const float* corc = cor + tc * 4;
  for (int k = 0; k < 256; ++k) {
    float4 c4 = *(const float4*)(corc + (size_t)k * 256);
#pragma unroll
    for (int rr = 0; rr < 8; ++rr) {
      float wv = Wl[(tr * 8 + rr) * 256 + k];
      acc[rr][0] = fmaf(wv, c4.x, acc[rr][0]);
      acc[rr][1] = fmaf(wv, c4.y, acc[rr][1]);
      acc[rr][2] = fmaf(wv, c4.z, acc[rr][2]);
      acc[rr][3] = fmaf(wv, c4.w, acc[rr][3]);
    }
  }
#pragma unroll
  for (int rr = 0; rr < 8; ++rr) {
    int row = row0 + tr * 8 + rr;
    float4 zv = *(const float4*)(z + (size_t)row * Ff + tc * 4);
    float x0 = zv.x + EPS_C * acc[rr][0];
    float x1 = zv.y + EPS_C * acc[rr][1];
    float x2 = zv.z + EPS_C * acc[rr][2];
    float x3 = zv.w + EPS_C * acc[rr][3];
    ushort4 o;
    o.x = f2b(x0); o.y = f2b(x1); o.z = f2b(x2); o.w = f2b(x3);
    *(ushort4*)(z2b + (size_t)row * Ff + tc * 4) = o;
    float s = x0 * x0 + x1 * x1 + x2 * x2 + x3 * x3;
#pragma unroll
    for (int m = 1; m < 64; m <<= 1) s += __shfl_xor(s, m);
    if (tc == 0) norms[row] = fmaxf(sqrtf(s), 1e-8f);
  }
}

// ---------- K7: adjacency bitmask ----------
__global__ void k_adj(const int* __restrict__ ei, const int* __restrict__ ej,
                      unsigned int* __restrict__ adj) {
  int e = blockIdx.x * 256 + threadIdx.x;
  unsigned int i = (unsigned int)ei[e], j = (unsigned int)ej[e];
  size_t b1 = (size_t)i * Nn + j;
  size_t b2 = (size_t)j * Nn + i;
  atomicOr(&adj[b1 >> 5], 1u << (b1 & 31));
  atomicOr(&adj[b2 >> 5], 1u << (b2 & 31));
}

// ---------- K8: per-edge cosine, batched ----------
__global__ __launch_bounds__(256) void k_edge(const int* __restrict__ ei,
                       const int* __restrict__ ej,
                       const unsigned short* __restrict__ z2b,
                       const float* __restrict__ norms,
                       float* __restrict__ scores, float* __restrict__ deg) {
  int t = threadIdx.x;
  int wv = t >> 6, lane = t & 63;
  int half = lane >> 5;
  int l32 = lane & 31;
  int gw = blockIdx.x * 4 + wv;
  int ebase = gw * 32;
#pragma unroll 2
  for (int it = 0; it < 16; ++it) {
    int e = ebase + it * 2 + half;
    int i = ei[e], j = ej[e];
    uint4 ua = *(const uint4*)(z2b + (size_t)i * Ff + l32 * 8);
    uint4 ub = *(const uint4*)(z2b + (size_t)j * Ff + l32 * 8);
    float d = 0.f;
    const uint32_t* pa = (const uint32_t*)&ua;
    const uint32_t* pb = (const uint32_t*)&ub;
#pragma unroll
    for (int q = 0; q < 4; ++q) {
      union { uint32_t u; float f; } alo, ahi, blo, bhi;
      alo.u = pa[q] << 16;  ahi.u = pa[q] & 0xffff0000u;
      blo.u = pb[q] << 16;  bhi.u = pb[q] & 0xffff0000u;
      d = fmaf(alo.f, blo.f, d);
      d = fmaf(ahi.f, bhi.f, d);
    }
#pragma unroll
    for (int m = 1; m < 32; m <<= 1) d += __shfl_xor(d, m);
    if (l32 == 0) {
      float sim = d / (norms[i] * norms[j]);
      atomicAdd(&scores[i], sim);
      atomicAdd(&deg[i], 1.f);
    }
  }
}

// ---------- K10: fused penalty GEMM — pipelined (vmcnt(8) partial drains) ----------
__global__ __launch_bounds__(256, 2) void k_penalty(const unsigned short* __restrict__ z2b,
    const unsigned int* __restrict__ adj, double* __restrict__ psum) {
  // triangular decode: 2080 blocks -> (br, bc), br <= bc
  int tb = blockIdx.x;
  int br = (int)(64.5 - sqrt(64.5 * 64.5 - 2.0 * (double)tb));
  while ((br + 1) * 64 - ((br + 1) * br) / 2 <= tb) ++br;
  while (br * 64 - (br * (br - 1)) / 2 > tb) --br;
  int bc = br + (tb - (br * 64 - (br * (br - 1)) / 2));

  __shared__ __align__(16) unsigned short LB[32768];  // 64 KB: 2 phase-buffers x (A 16KB + B 16KB)
  int t = threadIdx.x;
  int lane = t & 63;
  int wv = t >> 6;
  int wr = wv >> 1, wc = wv & 1;             // 2x2 waves, each 64x64
  int quad = lane >> 4;
  int l15 = lane & 15;
  int arow0 = br * 128, brow0 = bc * 128;

  f32x4 acc[4][4];
#pragma unroll
  for (int i = 0; i < 4; ++i)
#pragma unroll
    for (int j = 0; j < 4; ++j) acc[i][j] = (f32x4){0.f, 0.f, 0.f, 0.f};

  // stage phase p (64-wide K panel) into ping-pong buffer: 8 loads/thread
#define ISSUE_PHASE(p)                                                                   \
  {                                                                                      \
    unsigned short* buf = LB + ((p) & 1) * 16384;                                        \
    int k0 = (p) * 64;                                                                   \
    _Pragma("unroll")                                                                    \
    for (int it = 0; it < 4; ++it) {                                                     \
      int s = it * 256 + t;                                                              \
      int r = s >> 3;                                                                    \
      int g = (s & 7) ^ (r & 7);                                                         \
      const unsigned short* ga = z2b + (size_t)(arow0 + r) * Ff + k0 + g * 8;            \
      const unsigned short* gb = z2b + (size_t)(brow0 + r) * Ff + k0 + g * 8;            \
      __builtin_amdgcn_global_load_lds((const __attribute__((address_space(1))) void*)ga,\
                                       (__attribute__((address_space(3))) void*)(buf + s * 8),      \
                                       16, 0, 0);                                        \
      __builtin_amdgcn_global_load_lds((const __attribute__((address_space(1))) void*)gb,\
                                       (__attribute__((address_space(3))) void*)(buf + 8192 + s * 8),\
                                       16, 0, 0);                                        \
    }                                                                                    \
  }

  ISSUE_PHASE(0)
  ISSUE_PHASE(1)
#pragma unroll
  for (int p = 0; p < 4; ++p) {
    if (p < 3) __builtin_amdgcn_s_waitcnt(0xF78);   // vmcnt(8): this phase's 8 loads done, next 8 in flight
    else       __builtin_amdgcn_s_waitcnt(0xF70);   // vmcnt(0)
    __builtin_amdgcn_s_barrier();
    const unsigned short* As = LB + (p & 1) * 16384;
    const unsigned short* Bs = As + 8192;
#pragma unroll
    for (int kc = 0; kc < 2; ++kc) {
      bf16x8 afr[4], bfr[4];
#pragma unroll
      for (int mt = 0; mt < 4; ++mt) {
        int rA = wr * 64 + mt * 16 + l15;
        int g = kc * 4 + quad;
        int gl = g ^ (rA & 7);
        afr[mt] = *(const bf16x8*)(As + ((size_t)rA * 8 + gl) * 8);
      }
#pragma unroll
      for (int nt = 0; nt < 4; ++nt) {
        int rB = wc * 64 + nt * 16 + l15;
        int g = kc * 4 + quad;
        int gl = g ^ (rB & 7);
        bfr[nt] = *(const bf16x8*)(Bs + ((size_t)rB * 8 + gl) * 8);
      }
#pragma unroll
      for (int mt = 0; mt < 4; ++mt)
#pragma unroll
        for (int nt = 0; nt < 4; ++nt)
          acc[mt][nt] = __builtin_amdgcn_mfma_f32_16x16x32_bf16(afr[mt], bfr[nt],
                                                                acc[mt][nt], 0, 0, 0);
    }
    __builtin_amdgcn_s_barrier();                   // all waves done reading buf[p&1]
    if (p < 2) ISSUE_PHASE(p + 2)                   // refill the buffer just freed
  }
#undef ISSUE_PHASE

  // epilogue: masked thresholded sum with symmetry weights
  float local = 0.f;
  int a_base = arow0 + wr * 64;
  int b_base = brow0 + wc * 64;              // 64-aligned
#pragma unroll
  for (int mt = 0; mt < 4; ++mt) {
#pragma unroll
    for (int r = 0; r < 4; ++r) {
      int a = a_base + mt * 16 + quad * 4 + r;
      uint64_t bits = *(const uint64_t*)(adj + (size_t)a * 256 + (b_base >> 5));
#pragma unroll
      for (int nt = 0; nt < 4; ++nt) {
        float v = acc[mt][nt][r];
        int boff = nt * 16 + l15;
        bool conn = (bits >> boff) & 1ull;
        float wgt;
        if (br != bc) wgt = 2.f;
        else {
          int b = b_base + boff;
          wgt = (a < b) ? 2.f : (a == b ? 1.f : 0.f);
        }
        if (!conn && v > THRESH) local += wgt * v;
      }
    }
  }
#pragma unroll
  for (int m = 1; m < 64; m <<= 1) local += __shfl_xor(local, m);
  __syncthreads();                           // done with LB; reuse as reduction scratch
  float* red = (float*)LB;
  if (lane == 0) red[wv] = local;
  __syncthreads();
  if (t == 0) atomicAdd(psum, (double)(red[0] + red[1] + red[2] + red[3]));
}

// ---------- K11: homophily reduce + combine ----------
__global__ void k_final(const float* __restrict__ scores, const float* __restrict__ deg,
                        const double* __restrict__ psum, float* __restrict__ out) {
  __shared__ float red[4];
  int t = threadIdx.x;
  float acc = 0.f;
#pragma unroll 4
  for (int it = 0; it < 32; ++it) {
    int n = it * 256 + t;
    float dg = deg[n];
    acc += scores[n] / (dg == 0.f ? 1.f : dg);
  }
#pragma unroll
  for (int m = 1; m < 64; m <<= 1) acc += __shfl_xor(acc, m);
  if ((t & 63) == 0) red[t >> 6] = acc;
  __syncthreads();
  if (t == 0) {
    double h = -(double)(red[0] + red[1] + red[2] + red[3]) / 8192.0;
    double p = (*psum) / (8192.0 * 8192.0);
    out[0] = (float)(h + p);
  }
}

extern "C" void kernel_launch(void* const* d_in, const int* in_sizes, int n_in,
                              void* d_out, int out_size, void* d_ws, size_t ws_size,
                              hipStream_t stream) {
  const float* z = (const float*)d_in[0];
  // d_in[1] = x_hat (unused by the reference)
  const int* ei = (const int*)d_in[2];
  const int* ej = ei + Ee;
  const int* k2u = (const int*)d_in[3];
  const int* u2k = (const int*)d_in[4];

  char* ws = (char*)d_ws;
  // zeroed region: [0, ZERO_BYTES)
  unsigned int* adj = (unsigned int*)(ws);               // 8 MiB
  float* colsum     = (float*)(ws + 8388608);            // 1 KiB
  float* scores     = (float*)(ws + 8389632);            // 32 KiB
  float* deg        = (float*)(ws + 8422400);            // 32 KiB
  double* psum      = (double*)(ws + 8455168);           // 8 B
  const size_t ZERO_BYTES = 8455176;
  // non-zeroed scratch
  float* covp       = (float*)(ws + 8455296);            // 16 x 256 KiB = 4 MiB
  unsigned short* zT  = (unsigned short*)(ws + 12649600); // 4 MiB
  unsigned short* z2b = (unsigned short*)(ws + 16843904); // 4 MiB
  float* cor        = (float*)(ws + 21038208);           // 256 KiB
  float* norms      = (float*)(ws + 21300352);           // 32 KiB

  hipMemsetAsync(d_ws, 0, ZERO_BYTES, stream);
  k_adj<<<1024, 256, 0, stream>>>(ei, ej, adj);
  k_transpose<<<dim3(128, 4), 256, 0, stream>>>(z, zT, colsum);
  k_covg<<<dim3(2, 2, 16), 256, 0, stream>>>(zT, covp);
  k_cor<<<256, 256, 0, stream>>>(covp, colsum, cor);
  k_z2<<<256, 256, 0, stream>>>(z, colsum, k2u, u2k, cor, z2b, norms);
  k_edge<<<2048, 256, 0, stream>>>(ei, ej, z2b, norms, scores, deg);
  k_penalty<<<2080, 256, 0, stream>>>(z2b, adj, psum);
  k_final<<<1, 256, 0, stream>>>(scores, deg, psum, (float*)d_out);
}